// Round 1
// 141.401 us; speedup vs baseline: 1.0836x; 1.0836x over previous
//
#include <hip/hip_runtime.h>
#include <hip/hip_fp16.h>
#include <math.h>

#define NPOS 13824   // 24*24*24
#define CDIM 64
#define BTCH 2
#define LOG2E 1.4426950408889634f
#define QSCALE (0.125f * LOG2E)

typedef _Float16 f16;
typedef f16 f16x8 __attribute__((ext_vector_type(8)));
typedef float f32x4 __attribute__((ext_vector_type(4)));

__device__ __forceinline__ unsigned int f2bf1(float f) {   // RNE float->bf16
  unsigned int u = __float_as_uint(f);
  return (u + 0x7FFFu + ((u >> 16) & 1u)) >> 16;
}

__device__ __forceinline__ unsigned int pkh2(float a, float b) {  // {lo=a, hi=b} f16 pair
  __half2 h = __floats2half2_rn(a, b);
  return *reinterpret_cast<unsigned int*>(&h);
}

// ---------------------------------------------------------------------------
// Kernel 1 (MFMA rewrite): one 256x64 f16 A-operand (rows 0-63 = Wq*QSCALE,
// 64-127 = Wg[:, :64], 128-255 = {K_c,V_c} interleaved) times the 64-ch x
// tile for 64 positions. f16 fragments from XOR-swizzled LDS; fp32 epilogue
// adds biases exactly. Outputs identical layouts to the previous version:
// Qb (pre-scaled Q), KVp (bf16 K|V packed), GXT ({gate_partial, x} pairs).
// Zeroes pool.
// ---------------------------------------------------------------------------
__global__ __launch_bounds__(256) void qkvg_kernel(
    const float* __restrict__ x,
    const float* __restrict__ Wq, const float* __restrict__ bq,
    const float* __restrict__ Wk, const float* __restrict__ bk,
    const float* __restrict__ Wv, const float* __restrict__ bv,
    const float* __restrict__ Wg,
    float* __restrict__ Qb, unsigned int* __restrict__ KVp,
    float* __restrict__ GXT, float* __restrict__ pool)
{
  __shared__ __align__(16) unsigned short ws[256*64];  // f16 weights, 32 KB
  __shared__ __align__(16) unsigned short xs[64*64];   // f16 x [pos][ch], 8 KB
  const int t  = threadIdx.x;
  const int bi = blockIdx.x;
  const int b  = bi / 216;
  const int n0 = (bi - b*216) * 64;
  if (bi == 0 && t < 128) pool[t] = 0.0f;

  // ---- stage weights: 1024 float4 rows-of-4, coalesced; row-XOR swizzle ----
  #pragma unroll
  for (int k = 0; k < 4; ++k) {
    const int u  = t + k*256;            // 0..1023
    const int r  = u >> 4;               // source row 0..63
    const int i0 = (u & 15) * 4;         // in-ch 0..60 step 4
    const float4 q4 = *(const float4*)&Wq[r*64  + i0];
    const float4 g4 = *(const float4*)&Wg[r*128 + i0];
    const float4 k4 = *(const float4*)&Wk[r*64  + i0];
    const float4 v4 = *(const float4*)&Wv[r*64  + i0];
    {
      const int rr = r;
      const int idx = (rr*64 + i0) ^ ((rr & 7) << 3);
      *(uint2*)&ws[idx] = make_uint2(pkh2(q4.x*QSCALE, q4.y*QSCALE),
                                     pkh2(q4.z*QSCALE, q4.w*QSCALE));
    }
    {
      const int rr = 64 + r;
      const int idx = (rr*64 + i0) ^ ((rr & 7) << 3);
      *(uint2*)&ws[idx] = make_uint2(pkh2(g4.x, g4.y), pkh2(g4.z, g4.w));
    }
    {
      const int rr = 128 + 2*r;          // K channel r
      const int idx = (rr*64 + i0) ^ ((rr & 7) << 3);
      *(uint2*)&ws[idx] = make_uint2(pkh2(k4.x, k4.y), pkh2(k4.z, k4.w));
    }
    {
      const int rr = 129 + 2*r;          // V channel r
      const int idx = (rr*64 + i0) ^ ((rr & 7) << 3);
      *(uint2*)&ws[idx] = make_uint2(pkh2(v4.x, v4.y), pkh2(v4.z, v4.w));
    }
  }
  // ---- stage x tile as f16 [pos][ch], coalesced along pos ----
  {
    const int p = t & 63;
    const size_t xb = (size_t)(b*64)*NPOS + n0 + p;
    #pragma unroll
    for (int k = 0; k < 8; ++k) {
      const int ch0 = (t >> 6) * 2 + k * 8;       // even channels
      const float a0 = x[xb + (size_t)ch0*NPOS];
      const float a1 = x[xb + (size_t)(ch0+1)*NPOS];
      const int idx = (p*64 + ch0) ^ ((p & 7) << 3);
      *(unsigned int*)&xs[idx] = pkh2(a0, a1);
    }
  }
  __syncthreads();

  const int l   = t & 63;
  const int w   = t >> 6;
  const int lr  = l & 15;              // fragment row (A) / col (B,C)
  const int lkb = (l >> 4) * 8;        // k-slot base (consistent for A and B)
  const int swz = (lr & 7) << 3;

  // B fragments: x (shared across all output row-frags)
  f16x8 Bf[4][2];
  #pragma unroll
  for (int nf = 0; nf < 4; ++nf)
    #pragma unroll
    for (int kk = 0; kk < 2; ++kk) {
      const int prow = nf*16 + lr;
      Bf[nf][kk] = *(const f16x8*)&xs[(prow*64 + kk*32 + lkb) ^ swz];
    }
  // A fragments: this wave's 64 output rows
  f16x8 Af[4][2];
  #pragma unroll
  for (int f = 0; f < 4; ++f)
    #pragma unroll
    for (int kk = 0; kk < 2; ++kk) {
      const int row = (w*4 + f)*16 + lr;
      Af[f][kk] = *(const f16x8*)&ws[(row*64 + kk*32 + lkb) ^ swz];
    }
  f32x4 acc[4][4];
  #pragma unroll
  for (int f = 0; f < 4; ++f)
    #pragma unroll
    for (int nf = 0; nf < 4; ++nf) {
      f32x4 z = {0.f, 0.f, 0.f, 0.f};
      z = __builtin_amdgcn_mfma_f32_16x16x32_f16(Af[f][0], Bf[nf][0], z, 0, 0, 0);
      acc[f][nf] = __builtin_amdgcn_mfma_f32_16x16x32_f16(Af[f][1], Bf[nf][1], z, 0, 0, 0);
    }

  // ---- epilogue: C/D mapping col=lane&15 (pos), row=(lane>>4)*4+reg (ch) ----
  const int rsub  = (l >> 4) * 4;
  const int pbase = b*NPOS + n0;
  if (w == 0) {                    // ---- Q: add bq*QSCALE, float4 stores ----
    #pragma unroll
    for (int f = 0; f < 4; ++f) {
      const int ch0 = f*16 + rsub;
      const float4 bq4 = *(const float4*)&bq[ch0];
      #pragma unroll
      for (int nf = 0; nf < 4; ++nf) {
        const int p = pbase + nf*16 + lr;
        const float4 o = make_float4(fmaf(bq4.x, QSCALE, acc[f][nf].x),
                                     fmaf(bq4.y, QSCALE, acc[f][nf].y),
                                     fmaf(bq4.z, QSCALE, acc[f][nf].z),
                                     fmaf(bq4.w, QSCALE, acc[f][nf].w));
        *(float4*)&Qb[(size_t)p*64 + ch0] = o;
      }
    }
  } else if (w == 1) {             // ---- G: interleave {g, x} pairs ----
    #pragma unroll
    for (int f = 0; f < 4; ++f) {
      const int ch0 = f*16 + rsub;
      #pragma unroll
      for (int nf = 0; nf < 4; ++nf) {
        const int pl = n0 + nf*16 + lr;          // pos within batch
        const int p  = pbase + nf*16 + lr;
        const float xv0 = x[(size_t)(b*64 + ch0+0)*NPOS + pl];
        const float xv1 = x[(size_t)(b*64 + ch0+1)*NPOS + pl];
        const float xv2 = x[(size_t)(b*64 + ch0+2)*NPOS + pl];
        const float xv3 = x[(size_t)(b*64 + ch0+3)*NPOS + pl];
        const float4 o0 = make_float4(acc[f][nf].x, xv0, acc[f][nf].y, xv1);
        const float4 o1 = make_float4(acc[f][nf].z, xv2, acc[f][nf].w, xv3);
        *(float4*)&GXT[((size_t)p*64 + ch0)*2]     = o0;
        *(float4*)&GXT[((size_t)p*64 + ch0)*2 + 4] = o1;
      }
    }
  } else {                         // ---- K|V: bf16 pack, uint2 stores ----
    #pragma unroll
    for (int f = 0; f < 4; ++f) {
      const int c0 = (w - 2)*32 + f*8 + (l >> 4)*2;   // even channel base
      const float2 bk2 = *(const float2*)&bk[c0];
      const float2 bv2 = *(const float2*)&bv[c0];
      #pragma unroll
      for (int nf = 0; nf < 4; ++nf) {
        const int p = pbase + nf*16 + lr;
        uint2 kv;
        kv.x = (f2bf1(acc[f][nf].x + bk2.x) << 16) | f2bf1(acc[f][nf].y + bv2.x);
        kv.y = (f2bf1(acc[f][nf].z + bk2.y) << 16) | f2bf1(acc[f][nf].w + bv2.y);
        *(uint2*)&KVp[(size_t)p*64 + c0] = kv;
      }
    }
  }
}

// ---------------------------------------------------------------------------
// Kernel 2: tiled attention. XCD-swizzled 3x3x3 tiles; 5x5x5 bf16-packed K|V
// halo in LDS (31.25 KB, 4 blocks/CU). NO max pass (|logit| <= ~2, exp2 is
// safe; softmax is shift-invariant). Single streaming softmax pass, TWO
// positions per wave iteration for ILP. Gate weights bf16-packed in VGPRs.
// Coalesced (N,C) result into QOT (aliases Qb).
// ---------------------------------------------------------------------------
__global__ __launch_bounds__(256, 4) void attn_kernel(
    float* __restrict__ QOT,             // in: Q (N,C, pre-scaled); out: fin
    const unsigned int* __restrict__ KVp,
    const float* __restrict__ GXT,
    const float* __restrict__ bk, const float* __restrict__ bv,
    const float* __restrict__ memk, const float* __restrict__ memv,
    const float* __restrict__ Wg, const float* __restrict__ bg,
    float* __restrict__ pool)
{
  __shared__ __align__(16) unsigned int kvbuf[8000]; // 125 slots x 64 ch, bf16 K|V
  __shared__ __align__(16) float alsA[256];
  __shared__ __align__(16) float alsB[256];
  const int t = threadIdx.x;
  const int c = t & 63;
  const int w = t >> 6;

  // stage Wg[:,64:] via padded-65 LDS transpose (overlay kvbuf), pack to bf16
  {
    float* wgt2 = (float*)kvbuf;
    #pragma unroll
    for (int k = 0; k < 16; ++k) {
      int u = t + k*256;
      int cp = u >> 6, j = u & 63;
      wgt2[j*65 + cp] = Wg[cp*128 + 64 + j];
    }
  }
  __syncthreads();
  unsigned int wg2p[32];                 // bf16 pair: lo=even j, hi=odd j
  {
    const float* wgt2 = (const float*)kvbuf;
    #pragma unroll
    for (int j2 = 0; j2 < 32; ++j2) {
      unsigned lo = f2bf1(wgt2[(2*j2)*65 + c]);
      unsigned hi = f2bf1(wgt2[(2*j2+1)*65 + c]);
      wg2p[j2] = lo | (hi << 16);
    }
  }
  float mk[5], mv[5];
  #pragma unroll
  for (int m = 0; m < 5; ++m) { mk[m] = memk[c*5 + m]; mv[m] = memv[c*5 + m]; }
  const float bg_c = bg[c];
  __syncthreads();

  // XCD-aware swizzle: bi&7 = XCD; contiguous 128-tile slab per XCD for L2 reuse
  const int bi = (int)(blockIdx.x & 7) * 128 + (int)(blockIdx.x >> 3);
  const int b  = bi >> 9;                 // 512 tiles (8x8x8) per batch
  const int tb = bi & 511;
  const int h0 = (tb >> 6) * 3;
  const int d0 = ((tb >> 3) & 7) * 3;
  const int w0 = (tb & 7) * 3;
  const int bN = b * NPOS;

  // stage 5x5x5 packed K/V halo (already bf16-packed in global; OOB -> bias)
  for (int u = t; u < 125*16; u += 256) {
    int pos = u >> 4, q4 = u & 15;
    int ph = pos / 25, pr = pos - ph*25;
    int pd = pr / 5,  pw = pr - pd*5;
    int hh = h0 - 1 + ph, dd = d0 - 1 + pd, ww = w0 - 1 + pw;
    bool inb = ((unsigned)hh < 24u) && ((unsigned)dd < 24u) && ((unsigned)ww < 24u);
    uint4 kv;
    if (inb) {
      kv = *(const uint4*)(KVp + ((size_t)(bN + hh*576 + dd*24 + ww))*64 + q4*4);
    } else {
      const float4 kf = ((const float4*)bk)[q4];
      const float4 vf = ((const float4*)bv)[q4];
      kv.x = (f2bf1(kf.x) << 16) | f2bf1(vf.x);
      kv.y = (f2bf1(kf.y) << 16) | f2bf1(vf.y);
      kv.z = (f2bf1(kf.z) << 16) | f2bf1(vf.z);
      kv.w = (f2bf1(kf.w) << 16) | f2bf1(vf.w);
    }
    *(uint4*)&kvbuf[pos*64 + q4*4] = kv;
  }
  __syncthreads();

  float pacc = 0.0f;
  // two positions (li, li+4) per iteration; independent chains for ILP
  for (int li = w; li < 27; li += 8) {
    const int liB0 = li + 4;
    const bool hasB = liB0 < 27;          // wave-uniform
    const int liB = hasB ? liB0 : li;

    const int lhA = li / 9,  lrA = li - lhA*9;
    const int ldA = lrA / 3, lwA = lrA - ldA*3;
    const int pA  = bN + (h0+lhA)*576 + (d0+ldA)*24 + (w0+lwA);
    const int hbA = (lhA*25 + ldA*5 + lwA)*64 + c;
    const int lhB = liB / 9,  lrB = liB - lhB*9;
    const int ldB = lrB / 3,  lwB = lrB - ldB*3;
    const int pB  = bN + (h0+lhB)*576 + (d0+ldB)*24 + (w0+lwB);
    const int hbB = (lhB*25 + ldB*5 + lwB)*64 + c;

    const float qA = QOT[pA*64 + c];      // pre-scaled by 0.125*log2e
    const float qB = QOT[pB*64 + c];
    const float2 gxA = *(const float2*)&GXT[(size_t)(pA*64 + c)*2];
    const float2 gxB = *(const float2*)&GXT[(size_t)(pB*64 + c)*2];

    // single-pass softmax (no max subtraction), both positions interleaved
    float sA0 = 0.f, sA1 = 0.f, oA0 = 0.f, oA1 = 0.f;
    float sB0 = 0.f, sB1 = 0.f, oB0 = 0.f, oB1 = 0.f;
    #pragma unroll
    for (int m = 0; m < 5; ++m) {
      const float pfA = __builtin_amdgcn_exp2f(qA * mk[m]);
      const float pfB = __builtin_amdgcn_exp2f(qB * mk[m]);
      if (m & 1) { sA1 += pfA; oA1 = fmaf(pfA, mv[m], oA1);
                   sB1 += pfB; oB1 = fmaf(pfB, mv[m], oB1); }
      else       { sA0 += pfA; oA0 = fmaf(pfA, mv[m], oA0);
                   sB0 += pfB; oB0 = fmaf(pfB, mv[m], oB0); }
    }
    const unsigned int* kvA = &kvbuf[hbA];
    const unsigned int* kvB = &kvbuf[hbB];
    #pragma unroll
    for (int i = 0; i < 3; ++i)
      #pragma unroll
      for (int j = 0; j < 3; ++j)
        #pragma unroll
        for (int l = 0; l < 3; ++l) {
          const int s4  = i*9 + j*3 + l;
          const int off = (i*25 + j*5 + l)*64;
          const unsigned a = kvA[off], bb2 = kvB[off];
          const float kA = __uint_as_float(a & 0xFFFF0000u);
          const float vA = __uint_as_float(a << 16);
          const float kB = __uint_as_float(bb2 & 0xFFFF0000u);
          const float vB = __uint_as_float(bb2 << 16);
          const float pfA = __builtin_amdgcn_exp2f(qA * kA);
          const float pfB = __builtin_amdgcn_exp2f(qB * kB);
          if (s4 & 1) { sA1 += pfA; oA1 = fmaf(pfA, vA, oA1);
                        sB1 += pfB; oB1 = fmaf(pfB, vB, oB1); }
          else        { sA0 += pfA; oA0 = fmaf(pfA, vA, oA0);
                        sB0 += pfB; oB0 = fmaf(pfB, vB, oB0); }
        }
    const float attA = (oA0 + oA1) * __builtin_amdgcn_rcpf(sA0 + sA1);
    const float attB = (oB0 + oB1) * __builtin_amdgcn_rcpf(sB0 + sB1);

    alsA[w*64 + c] = attA;                // wave-local broadcast buffers
    alsB[w*64 + c] = attB;
    float gA0 = gxA.x + bg_c, gA1 = 0.f, gA2 = 0.f, gA3 = 0.f;
    float gB0 = gxB.x + bg_c, gB1 = 0.f, gB2 = 0.f, gB3 = 0.f;
    #pragma unroll
    for (int j4 = 0; j4 < 16; ++j4) {
      const float4 a4 = *(const float4*)&alsA[w*64 + j4*4];
      const float4 b4 = *(const float4*)&alsB[w*64 + j4*4];
      const unsigned pk0 = wg2p[2*j4], pk1 = wg2p[2*j4+1];
      const float w0f = __uint_as_float(pk0 << 16);
      const float w1f = __uint_as_float(pk0 & 0xFFFF0000u);
      const float w2f = __uint_as_float(pk1 << 16);
      const float w3f = __uint_as_float(pk1 & 0xFFFF0000u);
      gA0 = fmaf(w0f, a4.x, gA0); gB0 = fmaf(w0f, b4.x, gB0);
      gA1 = fmaf(w1f, a4.y, gA1); gB1 = fmaf(w1f, b4.y, gB1);
      gA2 = fmaf(w2f, a4.z, gA2); gB2 = fmaf(w2f, b4.z, gB2);
      gA3 = fmaf(w3f, a4.w, gA3); gB3 = fmaf(w3f, b4.w, gB3);
    }
    const float glA   = (gA0 + gA1) + (gA2 + gA3);
    const float glB   = (gB0 + gB1) + (gB2 + gB3);
    const float gateA = __builtin_amdgcn_rcpf(1.0f + __builtin_amdgcn_exp2f(-LOG2E * glA));
    const float gateB = __builtin_amdgcn_rcpf(1.0f + __builtin_amdgcn_exp2f(-LOG2E * glB));
    const float finA  = fmaf(gateA, attA - gxA.y, gxA.y);
    const float finB  = fmaf(gateB, attB - gxB.y, gxB.y);
    QOT[pA*64 + c] = finA;                // coalesced full-line (N,C) stores
    pacc += finA;
    if (hasB) { QOT[pB*64 + c] = finB; pacc += finB; }
  }

  // pool reduce: 4 waves -> 64 lanes -> 64 device atomics
  alsA[t] = pacc;
  __syncthreads();
  if (t < 64) {
    float s = alsA[t] + alsA[64 + t] + alsA[128 + t] + alsA[192 + t];
    atomicAdd(&pool[b*64 + t], s);
  }
}

// ---------------------------------------------------------------------------
// Kernel 3: (N,C) -> (B,C,N) transpose through padded LDS (full-line reads
// AND writes). Block 0 additionally runs the GRU cell.
// ---------------------------------------------------------------------------
__global__ __launch_bounds__(256) void outpool_kernel(
    const float* __restrict__ OT, float* __restrict__ out,
    const float* __restrict__ pool, const float* __restrict__ prev,
    const float* __restrict__ W_ih, const float* __restrict__ W_hh,
    const float* __restrict__ b_ih, const float* __restrict__ b_hh,
    float* __restrict__ outmem)
{
  __shared__ __align__(16) float ls[64*65];
  __shared__ __align__(16) float mu[128];
  __shared__ float gi[384];
  __shared__ float gh[384];
  const int t  = threadIdx.x;
  const int bi = blockIdx.x;
  const int b  = bi / 216;
  const int n0 = (bi - b*216) * 64;
  #pragma unroll
  for (int i = 0; i < 16; ++i) {
    int u = i*256 + t;
    int pos = u >> 6, cc = u & 63;
    ls[cc*65 + pos] = OT[(size_t)(b*NPOS + n0 + pos)*64 + cc];  // coalesced read
  }
  if (bi == 0 && t < 128) mu[t] = pool[t] * (1.0f / (float)NPOS);
  __syncthreads();
  #pragma unroll
  for (int i = 0; i < 16; ++i) {
    int u = i*256 + t;
    int cc = u >> 6, j = u & 63;
    out[(size_t)(b*64 + cc)*NPOS + n0 + j] = ls[cc*65 + j];     // coalesced write
  }
  if (bi != 0) return;

  // ---- GRU cell (block 0 only) ----
  for (int r = t; r < 384; r += 256) {
    const int b2 = r / 192, j = r - b2*192;
    const float4* wi4 = (const float4*)(W_ih + (size_t)j*64);
    const float4* wh4 = (const float4*)(W_hh + (size_t)j*64);
    const float4* mu4 = (const float4*)(mu + b2*64);
    const float4* pv4 = (const float4*)(prev + b2*64);
    float sgi = b_ih[j], sgh = b_hh[j];
    #pragma unroll
    for (int k = 0; k < 16; ++k) {
      float4 wv = wi4[k], m4 = mu4[k];
      sgi = fmaf(wv.x, m4.x, sgi); sgi = fmaf(wv.y, m4.y, sgi);
      sgi = fmaf(wv.z, m4.z, sgi); sgi = fmaf(wv.w, m4.w, sgi);
      float4 hv = wh4[k], p4 = pv4[k];
      sgh = fmaf(hv.x, p4.x, sgh); sgh = fmaf(hv.y, p4.y, sgh);
      sgh = fmaf(hv.z, p4.z, sgh); sgh = fmaf(hv.w, p4.w, sgh);
    }
    gi[r] = sgi; gh[r] = sgh;
  }
  __syncthreads();
  if (t < 128) {
    const int b2 = t >> 6, cc = t & 63;
    float ir = gi[b2*192 + cc],       hr = gh[b2*192 + cc];
    float iz = gi[b2*192 + 64 + cc],  hz = gh[b2*192 + 64 + cc];
    float ii = gi[b2*192 + 128 + cc], hn = gh[b2*192 + 128 + cc];
    float rr = 1.0f / (1.0f + __builtin_amdgcn_exp2f(-LOG2E * (ir + hr)));
    float zz = 1.0f / (1.0f + __builtin_amdgcn_exp2f(-LOG2E * (iz + hz)));
    float ng = tanhf(ii + rr * hn);
    outmem[t] = (1.0f - zz) * ng + zz * prev[t];
  }
}

// ---------------------------------------------------------------------------
extern "C" void kernel_launch(void* const* d_in, const int* in_sizes, int n_in,
                              void* d_out, int out_size, void* d_ws, size_t ws_size,
                              hipStream_t stream) {
  const float* x    = (const float*)d_in[0];
  const float* prev = (const float*)d_in[1];
  const float* Wq   = (const float*)d_in[2];
  const float* bq   = (const float*)d_in[3];
  const float* Wk   = (const float*)d_in[4];
  const float* bk   = (const float*)d_in[5];
  const float* Wv   = (const float*)d_in[6];
  const float* bv   = (const float*)d_in[7];
  const float* memk = (const float*)d_in[8];
  const float* memv = (const float*)d_in[9];
  const float* Wg   = (const float*)d_in[10];
  const float* bg   = (const float*)d_in[11];
  const float* W_ih = (const float*)d_in[12];
  const float* W_hh = (const float*)d_in[13];
  const float* b_ih = (const float*)d_in[14];
  const float* b_hh = (const float*)d_in[15];

  float* out    = (float*)d_out;                 // (B,C,H,D,W)
  float* outmem = out + (size_t)BTCH*CDIM*NPOS;  // (B,C)

  const size_t SZ = (size_t)BTCH*NPOS*CDIM;      // 1769472
  float* wsf       = (float*)d_ws;
  float* Qb        = wsf;                        // also attn output (OT)
  unsigned int* KVp = (unsigned int*)(wsf + SZ); // bf16 K|V packed
  float* GXT       = wsf + 2*SZ;                 // float2 per element: 2*SZ
  float* pool      = wsf + 4*SZ;                 // 128 floats

  qkvg_kernel<<<BTCH*216, 256, 0, stream>>>(x, Wq, bq, Wk, bk, Wv, bv, Wg,
                                            Qb, KVp, GXT, pool);
  attn_kernel<<<BTCH*512, 256, 0, stream>>>(Qb, KVp, GXT,
                                            bk, bv, memk, memv, Wg, bg, pool);
  outpool_kernel<<<BTCH*216, 256, 0, stream>>>(Qb, out, pool, prev,
                                               W_ih, W_hh, b_ih, b_hh, outmem);
}

// Round 2
// 139.738 us; speedup vs baseline: 1.0965x; 1.0119x over previous
//
#include <hip/hip_runtime.h>
#include <hip/hip_fp16.h>
#include <math.h>

#define NPOS 13824   // 24*24*24
#define CDIM 64
#define BTCH 2
#define LOG2E 1.4426950408889634f
#define QSCALE (0.125f * LOG2E)

typedef _Float16 f16;
typedef f16 f16x8 __attribute__((ext_vector_type(8)));
typedef float f32x4 __attribute__((ext_vector_type(4)));

__device__ __forceinline__ unsigned int f2bf1(float f) {   // RNE float->bf16
  unsigned int u = __float_as_uint(f);
  return (u + 0x7FFFu + ((u >> 16) & 1u)) >> 16;
}

__device__ __forceinline__ unsigned int pkh2(float a, float b) {  // {lo=a, hi=b} f16 pair
  __half2 h = __floats2half2_rn(a, b);
  return *reinterpret_cast<unsigned int*>(&h);
}

// ---------------------------------------------------------------------------
// Kernel 1 (MFMA): one 256x64 f16 A-operand (rows 0-63 = Wq*QSCALE,
// 64-127 = Wg[:, :64], 128-255 = {K_c,V_c} interleaved) times the 64-ch x
// tile for 64 positions. f16 fragments from XOR-swizzled LDS; fp32 epilogue
// adds biases exactly. Outputs: Qb (pre-scaled Q), KVp (bf16 K|V packed),
// GXT ({gate_partial, x} pairs). Zeroes pool.
// ---------------------------------------------------------------------------
__global__ __launch_bounds__(256) void qkvg_kernel(
    const float* __restrict__ x,
    const float* __restrict__ Wq, const float* __restrict__ bq,
    const float* __restrict__ Wk, const float* __restrict__ bk,
    const float* __restrict__ Wv, const float* __restrict__ bv,
    const float* __restrict__ Wg,
    float* __restrict__ Qb, unsigned int* __restrict__ KVp,
    float* __restrict__ GXT, float* __restrict__ pool)
{
  __shared__ __align__(16) unsigned short ws[256*64];  // f16 weights, 32 KB
  __shared__ __align__(16) unsigned short xs[64*64];   // f16 x [pos][ch], 8 KB
  const int t  = threadIdx.x;
  const int bi = blockIdx.x;
  const int b  = bi / 216;
  const int n0 = (bi - b*216) * 64;
  if (bi == 0 && t < 128) pool[t] = 0.0f;

  // ---- stage weights: 1024 float4 rows-of-4, coalesced; row-XOR swizzle ----
  #pragma unroll
  for (int k = 0; k < 4; ++k) {
    const int u  = t + k*256;            // 0..1023
    const int r  = u >> 4;               // source row 0..63
    const int i0 = (u & 15) * 4;         // in-ch 0..60 step 4
    const float4 q4 = *(const float4*)&Wq[r*64  + i0];
    const float4 g4 = *(const float4*)&Wg[r*128 + i0];
    const float4 k4 = *(const float4*)&Wk[r*64  + i0];
    const float4 v4 = *(const float4*)&Wv[r*64  + i0];
    {
      const int rr = r;
      const int idx = (rr*64 + i0) ^ ((rr & 7) << 3);
      *(uint2*)&ws[idx] = make_uint2(pkh2(q4.x*QSCALE, q4.y*QSCALE),
                                     pkh2(q4.z*QSCALE, q4.w*QSCALE));
    }
    {
      const int rr = 64 + r;
      const int idx = (rr*64 + i0) ^ ((rr & 7) << 3);
      *(uint2*)&ws[idx] = make_uint2(pkh2(g4.x, g4.y), pkh2(g4.z, g4.w));
    }
    {
      const int rr = 128 + 2*r;          // K channel r
      const int idx = (rr*64 + i0) ^ ((rr & 7) << 3);
      *(uint2*)&ws[idx] = make_uint2(pkh2(k4.x, k4.y), pkh2(k4.z, k4.w));
    }
    {
      const int rr = 129 + 2*r;          // V channel r
      const int idx = (rr*64 + i0) ^ ((rr & 7) << 3);
      *(uint2*)&ws[idx] = make_uint2(pkh2(v4.x, v4.y), pkh2(v4.z, v4.w));
    }
  }
  // ---- stage x tile as f16 [pos][ch], coalesced along pos ----
  {
    const int p = t & 63;
    const size_t xb = (size_t)(b*64)*NPOS + n0 + p;
    #pragma unroll
    for (int k = 0; k < 8; ++k) {
      const int ch0 = (t >> 6) * 2 + k * 8;       // even channels
      const float a0 = x[xb + (size_t)ch0*NPOS];
      const float a1 = x[xb + (size_t)(ch0+1)*NPOS];
      const int idx = (p*64 + ch0) ^ ((p & 7) << 3);
      *(unsigned int*)&xs[idx] = pkh2(a0, a1);
    }
  }
  __syncthreads();

  const int l   = t & 63;
  const int w   = t >> 6;
  const int lr  = l & 15;              // fragment row (A) / col (B,C)
  const int lkb = (l >> 4) * 8;        // k-slot base (consistent for A and B)
  const int swz = (lr & 7) << 3;

  // B fragments: x (shared across all output row-frags)
  f16x8 Bf[4][2];
  #pragma unroll
  for (int nf = 0; nf < 4; ++nf)
    #pragma unroll
    for (int kk = 0; kk < 2; ++kk) {
      const int prow = nf*16 + lr;
      Bf[nf][kk] = *(const f16x8*)&xs[(prow*64 + kk*32 + lkb) ^ swz];
    }
  // A fragments: this wave's 64 output rows
  f16x8 Af[4][2];
  #pragma unroll
  for (int f = 0; f < 4; ++f)
    #pragma unroll
    for (int kk = 0; kk < 2; ++kk) {
      const int row = (w*4 + f)*16 + lr;
      Af[f][kk] = *(const f16x8*)&ws[(row*64 + kk*32 + lkb) ^ swz];
    }
  f32x4 acc[4][4];
  #pragma unroll
  for (int f = 0; f < 4; ++f)
    #pragma unroll
    for (int nf = 0; nf < 4; ++nf) {
      f32x4 z = {0.f, 0.f, 0.f, 0.f};
      z = __builtin_amdgcn_mfma_f32_16x16x32_f16(Af[f][0], Bf[nf][0], z, 0, 0, 0);
      acc[f][nf] = __builtin_amdgcn_mfma_f32_16x16x32_f16(Af[f][1], Bf[nf][1], z, 0, 0, 0);
    }

  // ---- epilogue: C/D mapping col=lane&15 (pos), row=(lane>>4)*4+reg (ch) ----
  const int rsub  = (l >> 4) * 4;
  const int pbase = b*NPOS + n0;
  if (w == 0) {                    // ---- Q: add bq*QSCALE, float4 stores ----
    #pragma unroll
    for (int f = 0; f < 4; ++f) {
      const int ch0 = f*16 + rsub;
      const float4 bq4 = *(const float4*)&bq[ch0];
      #pragma unroll
      for (int nf = 0; nf < 4; ++nf) {
        const int p = pbase + nf*16 + lr;
        const float4 o = make_float4(fmaf(bq4.x, QSCALE, acc[f][nf].x),
                                     fmaf(bq4.y, QSCALE, acc[f][nf].y),
                                     fmaf(bq4.z, QSCALE, acc[f][nf].z),
                                     fmaf(bq4.w, QSCALE, acc[f][nf].w));
        *(float4*)&Qb[(size_t)p*64 + ch0] = o;
      }
    }
  } else if (w == 1) {             // ---- G: interleave {g, x} pairs ----
    #pragma unroll
    for (int f = 0; f < 4; ++f) {
      const int ch0 = f*16 + rsub;
      #pragma unroll
      for (int nf = 0; nf < 4; ++nf) {
        const int pl = n0 + nf*16 + lr;          // pos within batch
        const int p  = pbase + nf*16 + lr;
        const float xv0 = x[(size_t)(b*64 + ch0+0)*NPOS + pl];
        const float xv1 = x[(size_t)(b*64 + ch0+1)*NPOS + pl];
        const float xv2 = x[(size_t)(b*64 + ch0+2)*NPOS + pl];
        const float xv3 = x[(size_t)(b*64 + ch0+3)*NPOS + pl];
        const float4 o0 = make_float4(acc[f][nf].x, xv0, acc[f][nf].y, xv1);
        const float4 o1 = make_float4(acc[f][nf].z, xv2, acc[f][nf].w, xv3);
        *(float4*)&GXT[((size_t)p*64 + ch0)*2]     = o0;
        *(float4*)&GXT[((size_t)p*64 + ch0)*2 + 4] = o1;
      }
    }
  } else {                         // ---- K|V: bf16 pack, uint2 stores ----
    #pragma unroll
    for (int f = 0; f < 4; ++f) {
      const int c0 = (w - 2)*32 + f*8 + (l >> 4)*2;   // even channel base
      const float2 bk2 = *(const float2*)&bk[c0];
      const float2 bv2 = *(const float2*)&bv[c0];
      #pragma unroll
      for (int nf = 0; nf < 4; ++nf) {
        const int p = pbase + nf*16 + lr;
        uint2 kv;
        kv.x = (f2bf1(acc[f][nf].x + bk2.x) << 16) | f2bf1(acc[f][nf].y + bv2.x);
        kv.y = (f2bf1(acc[f][nf].z + bk2.y) << 16) | f2bf1(acc[f][nf].w + bv2.y);
        *(uint2*)&KVp[(size_t)p*64 + c0] = kv;
      }
    }
  }
}

// ---------------------------------------------------------------------------
// Kernel 2: tiled attention. XCD-swizzled 3x3x3 tiles; 5x5x5 bf16-packed K|V
// halo in LDS, CHANNEL-MAJOR layout kvbuf2[c*127 + pos] (stride 127 ==
// 31 mod 32 -> bank-bijective, conflict-free reads AND writes). A lane's 27
// neighbor slots are compile-time dword offsets 0..62 off one base ->
// compiler fuses into ds_read2_b32 pairs (~2x fewer LDS read instructions).
// NO max pass; single streaming softmax; TWO positions per wave iteration.
// ---------------------------------------------------------------------------
__global__ __launch_bounds__(256, 4) void attn_kernel(
    float* __restrict__ QOT,             // in: Q (N,C, pre-scaled); out: fin
    const unsigned int* __restrict__ KVp,
    const float* __restrict__ GXT,
    const float* __restrict__ bk, const float* __restrict__ bv,
    const float* __restrict__ memk, const float* __restrict__ memv,
    const float* __restrict__ Wg, const float* __restrict__ bg,
    float* __restrict__ pool)
{
  __shared__ __align__(16) unsigned int kvbuf2[64*127 + 128]; // ch-major, ~32.5 KB
  __shared__ __align__(16) float alsA[256];
  __shared__ __align__(16) float alsB[256];
  const int t = threadIdx.x;
  const int c = t & 63;
  const int w = t >> 6;

  // stage Wg[:,64:] via padded-65 LDS transpose (overlay kvbuf2), pack to bf16
  {
    float* wgt2 = (float*)kvbuf2;
    #pragma unroll
    for (int k = 0; k < 16; ++k) {
      int u = t + k*256;
      int cp = u >> 6, j = u & 63;
      wgt2[j*65 + cp] = Wg[cp*128 + 64 + j];
    }
  }
  __syncthreads();
  unsigned int wg2p[32];                 // bf16 pair: lo=even j, hi=odd j
  {
    const float* wgt2 = (const float*)kvbuf2;
    #pragma unroll
    for (int j2 = 0; j2 < 32; ++j2) {
      unsigned lo = f2bf1(wgt2[(2*j2)*65 + c]);
      unsigned hi = f2bf1(wgt2[(2*j2+1)*65 + c]);
      wg2p[j2] = lo | (hi << 16);
    }
  }
  float mk[5], mv[5];
  #pragma unroll
  for (int m = 0; m < 5; ++m) { mk[m] = memk[c*5 + m]; mv[m] = memv[c*5 + m]; }
  const float bg_c = bg[c];
  __syncthreads();

  // XCD-aware swizzle: bi&7 = XCD; contiguous 128-tile slab per XCD for L2 reuse
  const int bi = (int)(blockIdx.x & 7) * 128 + (int)(blockIdx.x >> 3);
  const int b  = bi >> 9;                 // 512 tiles (8x8x8) per batch
  const int tb = bi & 511;
  const int h0 = (tb >> 6) * 3;
  const int d0 = ((tb >> 3) & 7) * 3;
  const int w0 = (tb & 7) * 3;
  const int bN = b * NPOS;

  // stage 5x5x5 packed K/V halo into channel-major LDS (OOB -> bias)
  for (int u = t; u < 125*16; u += 256) {
    int pos = u >> 4, q4 = u & 15;
    int ph = pos / 25, pr = pos - ph*25;
    int pd = pr / 5,  pw = pr - pd*5;
    int hh = h0 - 1 + ph, dd = d0 - 1 + pd, ww = w0 - 1 + pw;
    bool inb = ((unsigned)hh < 24u) && ((unsigned)dd < 24u) && ((unsigned)ww < 24u);
    uint4 kv;
    if (inb) {
      kv = *(const uint4*)(KVp + ((size_t)(bN + hh*576 + dd*24 + ww))*64 + q4*4);
    } else {
      const float4 kf = ((const float4*)bk)[q4];
      const float4 vf = ((const float4*)bv)[q4];
      kv.x = (f2bf1(kf.x) << 16) | f2bf1(vf.x);
      kv.y = (f2bf1(kf.y) << 16) | f2bf1(vf.y);
      kv.z = (f2bf1(kf.z) << 16) | f2bf1(vf.z);
      kv.w = (f2bf1(kf.w) << 16) | f2bf1(vf.w);
    }
    kvbuf2[(4*q4 + 0)*127 + pos] = kv.x;   // 2-way bank aliasing only (free)
    kvbuf2[(4*q4 + 1)*127 + pos] = kv.y;
    kvbuf2[(4*q4 + 2)*127 + pos] = kv.z;
    kvbuf2[(4*q4 + 3)*127 + pos] = kv.w;
  }
  __syncthreads();

  float pacc = 0.0f;
  // two positions (li, li+4) per iteration; independent chains for ILP
  for (int li = w; li < 27; li += 8) {
    const int liB0 = li + 4;
    const bool hasB = liB0 < 27;          // wave-uniform
    const int liB = hasB ? liB0 : li;

    const int lhA = li / 9,  lrA = li - lhA*9;
    const int ldA = lrA / 3, lwA = lrA - ldA*3;
    const int pA  = bN + (h0+lhA)*576 + (d0+ldA)*24 + (w0+lwA);
    const int hbA = c*127 + lhA*25 + ldA*5 + lwA;   // channel-major halo base
    const int lhB = liB / 9,  lrB = liB - lhB*9;
    const int ldB = lrB / 3,  lwB = lrB - ldB*3;
    const int pB  = bN + (h0+lhB)*576 + (d0+ldB)*24 + (w0+lwB);
    const int hbB = c*127 + lhB*25 + ldB*5 + lwB;

    const float qA = QOT[pA*64 + c];      // pre-scaled by 0.125*log2e
    const float qB = QOT[pB*64 + c];
    const float2 gxA = *(const float2*)&GXT[(size_t)(pA*64 + c)*2];
    const float2 gxB = *(const float2*)&GXT[(size_t)(pB*64 + c)*2];

    // single-pass softmax (no max subtraction), both positions interleaved
    float sA0 = 0.f, sA1 = 0.f, oA0 = 0.f, oA1 = 0.f;
    float sB0 = 0.f, sB1 = 0.f, oB0 = 0.f, oB1 = 0.f;
    #pragma unroll
    for (int m = 0; m < 5; ++m) {
      const float pfA = __builtin_amdgcn_exp2f(qA * mk[m]);
      const float pfB = __builtin_amdgcn_exp2f(qB * mk[m]);
      if (m & 1) { sA1 += pfA; oA1 = fmaf(pfA, mv[m], oA1);
                   sB1 += pfB; oB1 = fmaf(pfB, mv[m], oB1); }
      else       { sA0 += pfA; oA0 = fmaf(pfA, mv[m], oA0);
                   sB0 += pfB; oB0 = fmaf(pfB, mv[m], oB0); }
    }
    const unsigned int* kvA = &kvbuf2[hbA];
    const unsigned int* kvB = &kvbuf2[hbB];
    #pragma unroll
    for (int i = 0; i < 3; ++i)
      #pragma unroll
      for (int j = 0; j < 3; ++j)
        #pragma unroll
        for (int l = 0; l < 3; ++l) {
          const int s4  = i*9 + j*3 + l;
          const int off = i*25 + j*5 + l;       // 0..62, ds_read2-fusable
          const unsigned a = kvA[off], bb2 = kvB[off];
          const float kA = __uint_as_float(a & 0xFFFF0000u);
          const float vA = __uint_as_float(a << 16);
          const float kB = __uint_as_float(bb2 & 0xFFFF0000u);
          const float vB = __uint_as_float(bb2 << 16);
          const float pfA = __builtin_amdgcn_exp2f(qA * kA);
          const float pfB = __builtin_amdgcn_exp2f(qB * kB);
          if (s4 & 1) { sA1 += pfA; oA1 = fmaf(pfA, vA, oA1);
                        sB1 += pfB; oB1 = fmaf(pfB, vB, oB1); }
          else        { sA0 += pfA; oA0 = fmaf(pfA, vA, oA0);
                        sB0 += pfB; oB0 = fmaf(pfB, vB, oB0); }
        }
    const float attA = (oA0 + oA1) * __builtin_amdgcn_rcpf(sA0 + sA1);
    const float attB = (oB0 + oB1) * __builtin_amdgcn_rcpf(sB0 + sB1);

    alsA[w*64 + c] = attA;                // wave-local broadcast buffers
    alsB[w*64 + c] = attB;
    float gA0 = gxA.x + bg_c, gA1 = 0.f, gA2 = 0.f, gA3 = 0.f;
    float gB0 = gxB.x + bg_c, gB1 = 0.f, gB2 = 0.f, gB3 = 0.f;
    #pragma unroll
    for (int j4 = 0; j4 < 16; ++j4) {
      const float4 a4 = *(const float4*)&alsA[w*64 + j4*4];
      const float4 b4 = *(const float4*)&alsB[w*64 + j4*4];
      const unsigned pk0 = wg2p[2*j4], pk1 = wg2p[2*j4+1];
      const float w0f = __uint_as_float(pk0 << 16);
      const float w1f = __uint_as_float(pk0 & 0xFFFF0000u);
      const float w2f = __uint_as_float(pk1 << 16);
      const float w3f = __uint_as_float(pk1 & 0xFFFF0000u);
      gA0 = fmaf(w0f, a4.x, gA0); gB0 = fmaf(w0f, b4.x, gB0);
      gA1 = fmaf(w1f, a4.y, gA1); gB1 = fmaf(w1f, b4.y, gB1);
      gA2 = fmaf(w2f, a4.z, gA2); gB2 = fmaf(w2f, b4.z, gB2);
      gA3 = fmaf(w3f, a4.w, gA3); gB3 = fmaf(w3f, b4.w, gB3);
    }
    const float glA   = (gA0 + gA1) + (gA2 + gA3);
    const float glB   = (gB0 + gB1) + (gB2 + gB3);
    const float gateA = __builtin_amdgcn_rcpf(1.0f + __builtin_amdgcn_exp2f(-LOG2E * glA));
    const float gateB = __builtin_amdgcn_rcpf(1.0f + __builtin_amdgcn_exp2f(-LOG2E * glB));
    const float finA  = fmaf(gateA, attA - gxA.y, gxA.y);
    const float finB  = fmaf(gateB, attB - gxB.y, gxB.y);
    QOT[pA*64 + c] = finA;                // coalesced full-line (N,C) stores
    pacc += finA;
    if (hasB) { QOT[pB*64 + c] = finB; pacc += finB; }
  }

  // pool reduce: 4 waves -> 64 lanes -> 64 device atomics
  alsA[t] = pacc;
  __syncthreads();
  if (t < 64) {
    float s = alsA[t] + alsA[64 + t] + alsA[128 + t] + alsA[192 + t];
    atomicAdd(&pool[b*64 + t], s);
  }
}

// ---------------------------------------------------------------------------
// Kernel 3: (N,C) -> (B,C,N) transpose through padded LDS (full-line reads
// AND writes). Block 0 additionally runs the GRU cell.
// ---------------------------------------------------------------------------
__global__ __launch_bounds__(256) void outpool_kernel(
    const float* __restrict__ OT, float* __restrict__ out,
    const float* __restrict__ pool, const float* __restrict__ prev,
    const float* __restrict__ W_ih, const float* __restrict__ W_hh,
    const float* __restrict__ b_ih, const float* __restrict__ b_hh,
    float* __restrict__ outmem)
{
  __shared__ __align__(16) float ls[64*65];
  __shared__ __align__(16) float mu[128];
  __shared__ float gi[384];
  __shared__ float gh[384];
  const int t  = threadIdx.x;
  const int bi = blockIdx.x;
  const int b  = bi / 216;
  const int n0 = (bi - b*216) * 64;
  #pragma unroll
  for (int i = 0; i < 16; ++i) {
    int u = i*256 + t;
    int pos = u >> 6, cc = u & 63;
    ls[cc*65 + pos] = OT[(size_t)(b*NPOS + n0 + pos)*64 + cc];  // coalesced read
  }
  if (bi == 0 && t < 128) mu[t] = pool[t] * (1.0f / (float)NPOS);
  __syncthreads();
  #pragma unroll
  for (int i = 0; i < 16; ++i) {
    int u = i*256 + t;
    int cc = u >> 6, j = u & 63;
    out[(size_t)(b*64 + cc)*NPOS + n0 + j] = ls[cc*65 + j];     // coalesced write
  }
  if (bi != 0) return;

  // ---- GRU cell (block 0 only) ----
  for (int r = t; r < 384; r += 256) {
    const int b2 = r / 192, j = r - b2*192;
    const float4* wi4 = (const float4*)(W_ih + (size_t)j*64);
    const float4* wh4 = (const float4*)(W_hh + (size_t)j*64);
    const float4* mu4 = (const float4*)(mu + b2*64);
    const float4* pv4 = (const float4*)(prev + b2*64);
    float sgi = b_ih[j], sgh = b_hh[j];
    #pragma unroll
    for (int k = 0; k < 16; ++k) {
      float4 wv = wi4[k], m4 = mu4[k];
      sgi = fmaf(wv.x, m4.x, sgi); sgi = fmaf(wv.y, m4.y, sgi);
      sgi = fmaf(wv.z, m4.z, sgi); sgi = fmaf(wv.w, m4.w, sgi);
      float4 hv = wh4[k], p4 = pv4[k];
      sgh = fmaf(hv.x, p4.x, sgh); sgh = fmaf(hv.y, p4.y, sgh);
      sgh = fmaf(hv.z, p4.z, sgh); sgh = fmaf(hv.w, p4.w, sgh);
    }
    gi[r] = sgi; gh[r] = sgh;
  }
  __syncthreads();
  if (t < 128) {
    const int b2 = t >> 6, cc = t & 63;
    float ir = gi[b2*192 + cc],       hr = gh[b2*192 + cc];
    float iz = gi[b2*192 + 64 + cc],  hz = gh[b2*192 + 64 + cc];
    float ii = gi[b2*192 + 128 + cc], hn = gh[b2*192 + 128 + cc];
    float rr = 1.0f / (1.0f + __builtin_amdgcn_exp2f(-LOG2E * (ir + hr)));
    float zz = 1.0f / (1.0f + __builtin_amdgcn_exp2f(-LOG2E * (iz + hz)));
    float ng = tanhf(ii + rr * hn);
    outmem[t] = (1.0f - zz) * ng + zz * prev[t];
  }
}

// ---------------------------------------------------------------------------
extern "C" void kernel_launch(void* const* d_in, const int* in_sizes, int n_in,
                              void* d_out, int out_size, void* d_ws, size_t ws_size,
                              hipStream_t stream) {
  const float* x    = (const float*)d_in[0];
  const float* prev = (const float*)d_in[1];
  const float* Wq   = (const float*)d_in[2];
  const float* bq   = (const float*)d_in[3];
  const float* Wk   = (const float*)d_in[4];
  const float* bk   = (const float*)d_in[5];
  const float* Wv   = (const float*)d_in[6];
  const float* bv   = (const float*)d_in[7];
  const float* memk = (const float*)d_in[8];
  const float* memv = (const float*)d_in[9];
  const float* Wg   = (const float*)d_in[10];
  const float* bg   = (const float*)d_in[11];
  const float* W_ih = (const float*)d_in[12];
  const float* W_hh = (const float*)d_in[13];
  const float* b_ih = (const float*)d_in[14];
  const float* b_hh = (const float*)d_in[15];

  float* out    = (float*)d_out;                 // (B,C,H,D,W)
  float* outmem = out + (size_t)BTCH*CDIM*NPOS;  // (B,C)

  const size_t SZ = (size_t)BTCH*NPOS*CDIM;      // 1769472
  float* wsf       = (float*)d_ws;
  float* Qb        = wsf;                        // also attn output (OT)
  unsigned int* KVp = (unsigned int*)(wsf + SZ); // bf16 K|V packed
  float* GXT       = wsf + 2*SZ;                 // float2 per element: 2*SZ
  float* pool      = wsf + 4*SZ;                 // 128 floats

  qkvg_kernel<<<BTCH*216, 256, 0, stream>>>(x, Wq, bq, Wk, bk, Wv, bv, Wg,
                                            Qb, KVp, GXT, pool);
  attn_kernel<<<BTCH*512, 256, 0, stream>>>(Qb, KVp, GXT,
                                            bk, bv, memk, memv, Wg, bg, pool);
  outpool_kernel<<<BTCH*216, 256, 0, stream>>>(Qb, out, pool, prev,
                                               W_ih, W_hh, b_ih, b_hh, outmem);
}